// Round 5
// baseline (27.052 us; speedup 1.0000x reference)
//
#include <hip/hip_runtime.h>
#include <math.h>

#define NRAYS 32768      // 16*64*32
#define NSPH  1024
#define SUBS  16         // subchunks per ray
#define SUBSZ 64         // spheres per subchunk
#define PAIRS 32         // sphere-pairs per subchunk
#define RPB   16         // rays per block
#define TPB   256
#define NBLK  (NRAYS / RPB)   // 2048 blocks

typedef float v2f __attribute__((ext_vector_type(2)));

// Forced VOP3P packed fp32 ops (gfx90a+/gfx950). Per-component rounding is
// bit-identical to scalar v_add_f32/v_mul_f32, so exactness vs numpy holds.
__device__ __forceinline__ v2f pk_add(v2f a, v2f b) {
    v2f d; asm("v_pk_add_f32 %0, %1, %2" : "=v"(d) : "v"(a), "v"(b)); return d;
}
__device__ __forceinline__ v2f pk_sub(v2f a, v2f b) {   // a - b
    v2f d; asm("v_pk_add_f32 %0, %1, %2 neg_lo:[0,1] neg_hi:[0,1]"
               : "=v"(d) : "v"(a), "v"(b)); return d;
}
__device__ __forceinline__ v2f pk_mul(v2f a, v2f b) {
    v2f d; asm("v_pk_mul_f32 %0, %1, %2" : "=v"(d) : "v"(a), "v"(b)); return d;
}

__global__ __launch_bounds__(256, 8) void sphere_kernel(
    const float* __restrict__ rays,
    const float* __restrict__ centers,
    const float* __restrict__ radii,
    float* __restrict__ out)
{
#pragma clang fp contract(off)
    // Pair-SoA layout: per subchunk of 64 spheres = 32 pairs = 64 float4, +1 pad
    // float4 => subchunk stride 1040B => the 4 broadcast addresses of a wave
    // land on disjoint bank quads (conflict-free).
    // pair p: sph[base+2p] = (x0,x1,y0,y1), sph[base+2p+1] = (z0,z1,r2_0,r2_1)
    __shared__ float4 sph[SUBS * (2 * PAIRS + 1)];   // 1040 * 16B = 16.6 KB
    __shared__ float  s_min[SUBS][RPB];
    __shared__ int    s_face[SUBS][RPB];

    const int tid = threadIdx.x;

    for (int p = tid; p < NSPH / 2; p += TPB) {
        const int g0 = 2 * p, g1 = 2 * p + 1;
        const float x0 = centers[3 * g0 + 0], y0 = centers[3 * g0 + 1], z0 = centers[3 * g0 + 2];
        const float x1 = centers[3 * g1 + 0], y1 = centers[3 * g1 + 1], z1 = centers[3 * g1 + 2];
        const float r0 = radii[g0], r1 = radii[g1];
        const int b4 = (p >> 5) * (2 * PAIRS + 1) + (p & 31) * 2;
        sph[b4 + 0] = make_float4(x0, x1, y0, y1);
        sph[b4 + 1] = make_float4(z0, z1, r0 * r0, r1 * r1);
    }
    __syncthreads();

    const int rl  = tid & (RPB - 1);   // ray within block, 0..15
    const int sub = tid >> 4;          // subchunk 0..15
    const int ray = blockIdx.x * RPB + rl;

    const float2* rp = (const float2*)(rays + ray * 6);
    const float2 q0 = rp[0], q1 = rp[1], q2 = rp[2];
    const float ox = q0.x, oy = q0.y, oz = q1.x;
    const float dx = q1.y, dy = q2.x, dz = q2.y;

    // a = ((dx*dx)+(dy*dy))+(dz*dz) -- numpy 3-elem sum order
    const float a    = ((dx * dx) + (dy * dy)) + (dz * dz);
    const float epsA = 1e-8f * a;      // w >= epsA  <=>  fl(w/a) >= 1e-8 (1-ulp band)
    const float hunA = 100.0f * a;     // deferred: active <=> bw < hunA
    const float INF  = __builtin_inff();

    const v2f ox2 = {ox, ox}, oy2 = {oy, oy}, oz2 = {oz, oz};
    const v2f dx2 = {dx, dx}, dy2 = {dy, dy}, dz2 = {dz, dz};
    const v2f a2  = {a, a};

    float cw   = INF;   // numerator of current min t (u = t*a before rounding)
    int   carg = 0;     // argmin within subchunk (first occurrence)

    const float4* __restrict__ spb = &sph[sub * (2 * PAIRS + 1)];
#pragma unroll 4
    for (int i = 0; i < PAIRS; ++i) {
        const float4 A = spb[2 * i];       // ds_read_b128
        const float4 B = spb[2 * i + 1];   // ds_read_b128
        const v2f X = {A.x, A.y}, Y = {A.z, A.w};
        const v2f Z = {B.x, B.y}, Q = {B.z, B.w};
        const v2f fx = pk_sub(ox2, X);
        const v2f fy = pk_sub(oy2, Y);
        const v2f fz = pk_sub(oz2, Z);
        const v2f m0 = pk_mul(dx2, fx);
        const v2f m1 = pk_mul(dy2, fy);
        const v2f m2 = pk_mul(dz2, fz);
        const v2f dt = pk_add(pk_add(m0, m1), m2);       // numpy sum order
        const v2f p0 = pk_mul(fx, fx);
        const v2f p1 = pk_mul(fy, fy);
        const v2f p2 = pk_mul(fz, fz);
        const v2f cc = pk_sub(pk_add(pk_add(p0, p1), p2), Q);
        // d = b^2-4ac = 4*z with identical rounding (power-of-2 scaling)
        const v2f zz = pk_sub(pk_mul(dt, dt), pk_mul(a2, cc));
        const float s0 = __builtin_amdgcn_sqrtf(zz.x);   // raw v_sqrt; NaN if z<0
        const float s1 = __builtin_amdgcn_sqrtf(zz.y);
        {   // sphere 2i
            const float w0 = s0 - dt.x;        // numerator of larger root
            const float w1 = -(dt.x + s0);     // numerator of smaller root, w1 <= w0
            const float u  = (w1 >= epsA) ? w1 : w0;     // min root >= eps
            const bool ok  = (zz.x > 0.0f) & (u >= epsA) & (u < cw);
            cw   = ok ? u : cw;
            carg = ok ? (2 * i) : carg;        // strict < => first occurrence
        }
        {   // sphere 2i+1
            const float w0 = s1 - dt.y;
            const float w1 = -(dt.y + s1);
            const float u  = (w1 >= epsA) ? w1 : w0;
            const bool ok  = (zz.y > 0.0f) & (u >= epsA) & (u < cw);
            cw   = ok ? u : cw;
            carg = ok ? (2 * i + 1) : carg;
        }
    }

    s_min[sub][rl]  = cw;
    s_face[sub][rl] = ((sub & 3) << 6) | carg;  // chunk-LOCAL face index (0..255)
    __syncthreads();

    // Epilogue: threads 0..15 handle one ray each.
    if (tid < RPB) {
        float bw   = INF;
        int   face = -1;
        for (int k = 0; k < SUBS; ++k) {
            const float mt = s_min[k][tid];
            if (mt < bw) { bw = mt; face = s_face[k][tid]; }  // earlier subchunk wins ties
        }
        // Deferred window test: any in-window u beats every u>=hunA in the min,
        // so bw<hunA <=> reference's any(mask); argmin unaffected.
        const bool active = bw < hunA;

        // Single IEEE division per ray: best = fl(u*/a) == reference's rounded t.
        const float best = active ? (bw / a) : 100.0f;

        float px = ox + (best * dx);
        float py = oy + (best * dy);
        float pz = oz + (best * dz);

        // reference: idx = clip(face,0,1023), face in [-1,255] (chunk-local bug kept)
        const int gidx = (active && face >= 0) ? face : 0;
        const int b4 = (gidx >> 6) * (2 * PAIRS + 1) + ((gidx & 63) >> 1) * 2;
        const int j  = gidx & 1;
        const float4 A = sph[b4];
        const float4 B = sph[b4 + 1];
        const float cxv = j ? A.y : A.x;
        const float cyv = j ? A.w : A.z;
        const float czv = j ? B.y : B.x;
        const float ddx = px - cxv;
        const float ddy = py - cyv;
        const float ddz = pz - czv;
        float nrm = sqrtf(((ddx * ddx) + (ddy * ddy)) + (ddz * ddz));
        nrm = fmaxf(nrm, 1e-12f);
        const float nx = active ? (ddx / nrm) : 0.0f;
        const float ny = active ? (ddy / nrm) : 0.0f;
        const float nz = active ? (ddz / nrm) : 0.0f;
        px = px + (nx * 1e-5f);
        py = py + (ny * 1e-5f);
        pz = pz + (nz * 1e-5f);

        const int r = blockIdx.x * RPB + tid;
        float* outp = out;                 // p: 3*NRAYS
        float* outn = out + NRAYS * 3;     // n: 3*NRAYS
        float* outd = out + NRAYS * 6;     // best_dists: NRAYS
        float* outa = out + NRAYS * 7;     // out_active: NRAYS

        outp[r * 3 + 0] = px;
        outp[r * 3 + 1] = py;
        outp[r * 3 + 2] = pz;
        outn[r * 3 + 0] = nx;
        outn[r * 3 + 1] = ny;
        outn[r * 3 + 2] = nz;
        outd[r] = best;
        outa[r] = active ? 1.0f : 0.0f;
    }
}

extern "C" void kernel_launch(void* const* d_in, const int* in_sizes, int n_in,
                              void* d_out, int out_size, void* d_ws, size_t ws_size,
                              hipStream_t stream) {
    const float* rays    = (const float*)d_in[0];
    const float* centers = (const float*)d_in[1];
    const float* radii   = (const float*)d_in[2];
    float* out = (float*)d_out;

    dim3 grid(NBLK);     // 2048 blocks
    dim3 block(TPB);     // 256 threads
    hipLaunchKernelGGL(sphere_kernel, grid, block, 0, stream,
                       rays, centers, radii, out);
}